// Round 1
// baseline (913.152 us; speedup 1.0000x reference)
//
#include <hip/hip_runtime.h>
#include <stdint.h>

// Problem constants
// B=8, R=40, L=128, IN=256, WDIM=512, DREL=15, F=200 (pad 256), HID=300

#define LK(x) ((x) > 0.f ? (x) : 0.01f*(x))

typedef __attribute__((ext_vector_type(8))) short s16x8;
typedef __attribute__((ext_vector_type(4))) float f32x4;

__device__ __forceinline__ unsigned short f2bf(float f) {
  union { float f; unsigned int u; } v; v.f = f;
  unsigned int u = v.u;
  return (unsigned short)((u + 0x7FFFu + ((u >> 16) & 1u)) >> 16);
}

__device__ __forceinline__ void gload_lds16(const void* g, void* l) {
  __builtin_amdgcn_global_load_lds(
      (const __attribute__((address_space(1))) unsigned int*)g,
      (__attribute__((address_space(3))) unsigned int*)l, 16, 0, 0);
}

// ---------------- Kernel A: small preps --------------------------------
// roles: bid 0..7 h[b][300]; 8..15 trans[b][200]; 16..79 word_h->bf16;
//        80..143 arc_W slices ->bf16; 144 RW^T bf16 [256][72]
__global__ __launch_bounds__(256) void k_prep(
    const float* __restrict__ e1, const float* __restrict__ e2,
    const float* __restrict__ rel, const float* __restrict__ aW,
    const float* __restrict__ ffW, const float* __restrict__ ffb,
    const float* __restrict__ itW, const float* __restrict__ itb,
    const float* __restrict__ wh,
    unsigned short* __restrict__ whbf, unsigned short* __restrict__ aw1,
    unsigned short* __restrict__ aw2, unsigned short* __restrict__ rwt,
    float* __restrict__ hg, float* __restrict__ trans)
{
  int bid = blockIdx.x, t = threadIdx.x;
  if (bid < 16) {
    __shared__ float in_lds[1024];
    int b = bid & 7;
    for (int k = t; k < 1024; k += 256)
      in_lds[k] = (k < 512) ? e1[b*512 + k] : e2[b*512 + (k - 512)];
    __syncthreads();
    if (bid < 8) {
      for (int o = t; o < 300; o += 256) {
        const float4* wr = (const float4*)(ffW + (size_t)o*1024);
        float acc = ffb[o];
        for (int k = 0; k < 256; ++k) {
          float4 w = wr[k]; float4 v = *(const float4*)&in_lds[k*4];
          acc += w.x*v.x + w.y*v.y + w.z*v.z + w.w*v.w;
        }
        hg[b*300 + o] = LK(acc);
      }
    } else {
      for (int o = t; o < 200; o += 256) {
        const float4* wr = (const float4*)(itW + (size_t)o*1024);
        float acc = itb[o];
        for (int k = 0; k < 256; ++k) {
          float4 w = wr[k]; float4 v = *(const float4*)&in_lds[k*4];
          acc += w.x*v.x + w.y*v.y + w.z*v.z + w.w*v.w;
        }
        trans[b*200 + o] = LK(acc);
      }
    }
  } else if (bid < 80) {
    int id0 = (bid - 16)*256 + t;
    for (int v = id0; v < 131072; v += 64*256) {
      float4 x = ((const float4*)wh)[v];
      unsigned short* dst = whbf + (size_t)v*4;
      dst[0] = f2bf(x.x); dst[1] = f2bf(x.y); dst[2] = f2bf(x.z); dst[3] = f2bf(x.w);
    }
  } else if (bid < 144) {
    int id0 = (bid - 80)*256 + t;
    for (int e = id0; e < 131072; e += 64*256) {
      int o = e >> 9, k = e & 511;
      aw1[e] = f2bf(aW[(size_t)o*1039 + k]);
      aw2[e] = f2bf(aW[(size_t)o*1039 + 512 + k]);
    }
  } else {
    int o = t;  // 256 threads, one o each
    for (int r = 0; r < 40; ++r) {
      float s = 0.f;
      for (int d = 0; d < 15; ++d) s += rel[r*15 + d] * aW[(size_t)o*1039 + 1024 + d];
      rwt[o*72 + r] = f2bf(s);
    }
    for (int r = 40; r < 72; ++r) rwt[o*72 + r] = 0;
  }
}

// ---------------- Kernel B: P/Q GEMMs (MFMA) ---------------------------
// C[o][n=(b,j)] = sum_k aw[o][k]*wh[n][k]; one 16x16 tile per wave, K=512
__global__ __launch_bounds__(256) void k_pq(
    const unsigned short* __restrict__ whbf,
    const unsigned short* __restrict__ aw1,
    const unsigned short* __restrict__ aw2,
    float* __restrict__ Pg, float* __restrict__ Qg)
{
  int bid = blockIdx.x, t = threadIdx.x;
  int g = bid >> 8;
  int wv = t >> 6, l = t & 63, lm = l & 15, hi = l >> 4;
  int tile = (bid & 255)*4 + wv;
  int ot = tile & 15, nt = tile >> 4;
  const unsigned short* A = g ? aw2 : aw1;
  float* out = g ? Qg : Pg;
  int orow = ot*16 + lm, n = nt*16 + lm;
  f32x4 acc = {0.f, 0.f, 0.f, 0.f};
  const unsigned short* ap = A + (size_t)orow*512 + hi*8;
  const unsigned short* bp = whbf + (size_t)n*512 + hi*8;
#pragma unroll
  for (int kk = 0; kk < 16; ++kk) {
    s16x8 af = *(const s16x8*)(ap + kk*32);
    s16x8 bf = *(const s16x8*)(bp + kk*32);
    acc = __builtin_amdgcn_mfma_f32_16x16x32_bf16(af, bf, acc, 0, 0, 0);
  }
#pragma unroll
  for (int r = 0; r < 4; ++r)
    out[(size_t)n*256 + ot*16 + hi*4 + r] = acc[r];
}

// ---------------- Kernel C: filter factory -----------------------------
// filt_g[b][dc][f(256)][tap(9)][dl(32)] (+8 bf16 pad per f-row -> 296)
__global__ __launch_bounds__(256) void k_filt(
    const float* __restrict__ fw1, const float* __restrict__ fb1,
    const float* __restrict__ hg, unsigned short* __restrict__ filtg)
{
  __shared__ float hl[2400];  // [k 300][b 8]
  int t = threadIdx.x;
  for (int idx = t; idx < 2400; idx += 256) {
    int k = idx >> 3, bb = idx & 7;
    hl[idx] = hg[bb*300 + k];
  }
  __syncthreads();
  int row = blockIdx.x*256 + t;           // (f, d, tap) row, f up to 255
  int f = row / 2304;
  int rem = row - f*2304;
  int d = rem / 9, tap = rem - d*9;
  float acc[8] = {0,0,0,0,0,0,0,0};
  float bias = 0.f;
  if (f < 200) {
    const float4* wr = (const float4*)(fw1 + (size_t)row*300);
    bias = fb1[row];
    for (int kk = 0; kk < 75; ++kk) {
      float4 w = wr[kk];
#pragma unroll
      for (int e = 0; e < 4; ++e) {
        float we = (e==0)?w.x:((e==1)?w.y:((e==2)?w.z:w.w));
        int k = kk*4 + e;
        float4 ha = *(const float4*)&hl[k*8];
        float4 hb = *(const float4*)&hl[k*8 + 4];
        acc[0] += we*ha.x; acc[1] += we*ha.y; acc[2] += we*ha.z; acc[3] += we*ha.w;
        acc[4] += we*hb.x; acc[5] += we*hb.y; acc[6] += we*hb.z; acc[7] += we*hb.w;
      }
    }
  }
  int dc = d >> 5, dl = d & 31;
#pragma unroll
  for (int bb = 0; bb < 8; ++bb) {
    float v = (f < 200) ? LK(acc[bb] + bias) : 0.f;
    filtg[((size_t)(bb*8 + dc)*256 + f)*296 + tap*32 + dl] = f2bf(v);
  }
}

// ---------------- Kernel 2: arc -> mem_bank ----------------------------
// block=(b,i). S via MFMA E^T[128x64] @ RW[64x256]; epilogue adds
// marg*(P+Q)+bias, leaky, writes mem_bank[b][i][j][d=o] bf16.
__global__ __launch_bounds__(256) void k_arc(
    const float* __restrict__ energy,
    const unsigned short* __restrict__ rwt,
    const float* __restrict__ Pg, const float* __restrict__ Qg,
    const float* __restrict__ arcb,
    unsigned short* __restrict__ memb)
{
  __shared__ unsigned short Et[128*72];  // [j][r], r padded to 72, zeros >=40
  __shared__ float mpart[256];
  __shared__ float qlds[256];
  __shared__ float blds[256];
  int bid = blockIdx.x, t = threadIdx.x;
  int b = bid >> 7, i = bid & 127;
  int jj = t & 127, half = t >> 7;
  float macc = 0.f;
  for (int rr = 0; rr < 20; ++rr) {
    int r = half*20 + rr;
    float e = energy[(((size_t)b*40 + r)*128 + i)*128 + jj];
    e = fmaxf(e, 0.f);
    macc += e;
    Et[jj*72 + r] = f2bf(e);
  }
  mpart[t] = macc;
  if (t < 128) {
#pragma unroll
    for (int r = 40; r < 72; ++r) Et[t*72 + r] = 0;
  }
  qlds[t] = Qg[((size_t)(b*128 + i))*256 + t];
  blds[t] = arcb[t];
  __syncthreads();

  int wv = t >> 6, l = t & 63, lm = l & 15, hi = l >> 4;
  unsigned short* mout = memb + ((size_t)(b*128 + i))*128*256;
  for (int otl = 0; otl < 4; ++otl) {
    int oc = (wv*4 + otl)*16 + lm;
    const unsigned short* rp = rwt + oc*72 + hi*8;
    s16x8 bf0 = *(const s16x8*)rp;
    s16x8 bf1 = *(const s16x8*)(rp + 32);
    float q = qlds[oc], bias = blds[oc];
    for (int jt = 0; jt < 8; ++jt) {
      const unsigned short* ep = &Et[(jt*16 + lm)*72 + hi*8];
      s16x8 af0 = *(const s16x8*)ep;
      s16x8 af1 = *(const s16x8*)(ep + 32);
      f32x4 acc = {0.f,0.f,0.f,0.f};
      acc = __builtin_amdgcn_mfma_f32_16x16x32_bf16(af0, bf0, acc, 0, 0, 0);
      acc = __builtin_amdgcn_mfma_f32_16x16x32_bf16(af1, bf1, acc, 0, 0, 0);
#pragma unroll
      for (int r = 0; r < 4; ++r) {
        int j = jt*16 + hi*4 + r;
        float m = mpart[j] + mpart[128 + j];
        float p = Pg[((size_t)(b*128 + j))*256 + oc];
        float v = acc[r] + m*(p + q) + bias;
        v = LK(v);
        mout[(size_t)j*256 + oc] = f2bf(v);
      }
    }
  }
}

// ---------------- Kernel D: conv + fused leaky/maxpool -----------------
// block=(b, y, fc). C[x(128)][f(64)] via mfma 16x16x32, K=d chunks of 32,
// 9 taps accumulated. filt staged linearly (global layout pre-padded to
// match LDS); mem staged with pre-swizzled per-lane global source.
__global__ __launch_bounds__(256, 2) void k_conv(
    const unsigned short* __restrict__ filtg,
    const unsigned short* __restrict__ memb,
    float* __restrict__ part)
{
  __shared__ __align__(16) char smem[63232];
  char* lds_filt = smem;            // 64 f * 592 B = 37888
  char* lds_mem  = smem + 37888;    // 3 ky * 132 x * 64 B = 25344
  int bid = blockIdx.x, t = threadIdx.x;
  int y = bid % 126;
  int tmp = bid / 126;
  int fc = tmp & 3, b = tmp >> 2;
  int wv = t >> 6, l = t & 63, lm = l & 15, hi = l >> 4;
  int wx = wv & 1, wf = wv >> 1;

  f32x4 zero = {0.f,0.f,0.f,0.f};
  f32x4 acc[4][2];
#pragma unroll
  for (int xt = 0; xt < 4; ++xt) { acc[xt][0] = zero; acc[xt][1] = zero; }

  for (int dc = 0; dc < 8; ++dc) {
    const char* fs = (const char*)filtg + ((size_t)((b*8 + dc)*256 + fc*64))*592;
    for (int c = wv; c < 37; c += 4)
      gload_lds16(fs + ((size_t)c*64 + l)*16, lds_filt + c*1024);
    for (int c = wv; c < 25; c += 4) {
      int id = c*64 + l;
      if (id < 1584) {
        int ky = (id >= 1056) ? 2 : ((id >= 528) ? 1 : 0);
        int rem = id - ky*528;
        int x = rem >> 2, s = rem & 3;
        int cs = s ^ ((x >> 1) & 3);          // swizzled source chunk
        int xs = (x < 128) ? x : 127;          // clamp (discard columns)
        const char* ms = (const char*)memb +
            (((((size_t)(b*128 + y + ky))*128 + xs)*256) + dc*32 + cs*8)*2;
        gload_lds16(ms, lds_mem + c*1024);
      }
    }
    __syncthreads();
#pragma unroll
    for (int tap = 0; tap < 9; ++tap) {
      int ky = tap / 3, kx = tap - ky*3;
      s16x8 bfr[2];
#pragma unroll
      for (int ft = 0; ft < 2; ++ft)
        bfr[ft] = *(const s16x8*)(lds_filt + (wf*32 + ft*16 + lm)*592 + tap*64 + hi*16);
#pragma unroll
      for (int xt = 0; xt < 4; ++xt) {
        int x = wx*64 + xt*16 + lm + kx;
        int slot = hi ^ ((x >> 1) & 3);
        s16x8 af = *(const s16x8*)(lds_mem + ((ky*132 + x)*4 + slot)*16);
        acc[xt][0] = __builtin_amdgcn_mfma_f32_16x16x32_bf16(af, bfr[0], acc[xt][0], 0,0,0);
        acc[xt][1] = __builtin_amdgcn_mfma_f32_16x16x32_bf16(af, bfr[1], acc[xt][1], 0,0,0);
      }
    }
    __syncthreads();
  }

  // per-f max over this block's (x,y) footprint; leaky applied after max
  float pm0 = -3.4e38f, pm1 = -3.4e38f;
#pragma unroll
  for (int xt = 0; xt < 4; ++xt) {
    int xb = wx*64 + xt*16 + hi*4;
#pragma unroll
    for (int r = 0; r < 4; ++r) {
      if (xb + r < 126) {
        pm0 = fmaxf(pm0, acc[xt][0][r]);
        pm1 = fmaxf(pm1, acc[xt][1][r]);
      }
    }
  }
  pm0 = fmaxf(pm0, __shfl_xor(pm0, 16));
  pm0 = fmaxf(pm0, __shfl_xor(pm0, 32));
  pm1 = fmaxf(pm1, __shfl_xor(pm1, 16));
  pm1 = fmaxf(pm1, __shfl_xor(pm1, 32));
  float* red = (float*)smem;   // reuse LDS (after final barrier above)
  if (l < 16) {
    red[(wf*2 + wx)*32 + lm]      = pm0;
    red[(wf*2 + wx)*32 + 16 + lm] = pm1;
  }
  __syncthreads();
  if (t < 64) {
    int wfi = t >> 5, fi = t & 31;
    float v = fmaxf(red[(wfi*2 + 0)*32 + fi], red[(wfi*2 + 1)*32 + fi]);
    v = LK(v);
    part[((size_t)(b*126 + y))*256 + fc*64 + t] = v;
  }
}

// ---------------- Final: reduce over y, add transformed ----------------
__global__ __launch_bounds__(256) void k_final(
    const float* __restrict__ part, const float* __restrict__ trans,
    float* __restrict__ out)
{
  int b = blockIdx.x, t = threadIdx.x;
  if (t < 200) {
    float m = -3.4e38f;
    for (int yy = 0; yy < 126; ++yy)
      m = fmaxf(m, part[((size_t)(b*126 + yy))*256 + t]);
    out[b*200 + t] = trans[b*200 + t] + m;
  }
}

extern "C" void kernel_launch(void* const* d_in, const int* in_sizes, int n_in,
                              void* d_out, int out_size, void* d_ws, size_t ws_size,
                              hipStream_t stream)
{
  (void)in_sizes; (void)n_in; (void)out_size; (void)ws_size;
  const float* energy = (const float*)d_in[0];
  const float* word_h = (const float*)d_in[1];
  const float* e1     = (const float*)d_in[2];
  const float* e2     = (const float*)d_in[3];
  // d_in[4] sent_len unused
  const float* rel    = (const float*)d_in[5];
  const float* aW     = (const float*)d_in[6];
  const float* arcb   = (const float*)d_in[7];
  const float* ffW    = (const float*)d_in[8];
  const float* ffb    = (const float*)d_in[9];
  const float* fw1    = (const float*)d_in[10];
  const float* fb1    = (const float*)d_in[11];
  const float* itW    = (const float*)d_in[12];
  const float* itb    = (const float*)d_in[13];

  char* ws = (char*)d_ws;   // total required: 81,563,264 bytes
  unsigned short* whbf  = (unsigned short*)(ws + 0);         // 1,048,576
  unsigned short* aw1   = (unsigned short*)(ws + 1048576);   //   262,144
  unsigned short* aw2   = (unsigned short*)(ws + 1310720);   //   262,144
  unsigned short* rwt   = (unsigned short*)(ws + 1572864);   //    36,864
  float*          hg    = (float*)(ws + 1609728);            //     9,600
  float*          trans = (float*)(ws + 1619328);            //     6,400
  float*          Pg    = (float*)(ws + 1625728);            // 1,048,576
  float*          Qg    = (float*)(ws + 2674304);            // 1,048,576
  float*          part  = (float*)(ws + 3722880);            // 1,032,192
  unsigned short* filtg = (unsigned short*)(ws + 4755072);   // 9,699,328
  unsigned short* memb  = (unsigned short*)(ws + 14454400);  // 67,108,864

  k_prep <<<145, 256, 0, stream>>>(e1, e2, rel, aW, ffW, ffb, itW, itb, word_h,
                                   whbf, aw1, aw2, rwt, hg, trans);
  k_pq   <<<512, 256, 0, stream>>>(whbf, aw1, aw2, Pg, Qg);
  k_filt <<<2304, 256, 0, stream>>>(fw1, fb1, hg, filtg);
  k_arc  <<<1024, 256, 0, stream>>>(energy, rwt, Pg, Qg, arcb, memb);
  k_conv <<<4032, 256, 0, stream>>>(filtg, memb, part);
  k_final<<<8, 256, 0, stream>>>(part, trans, (float*)d_out);
}

// Round 2
// 485.384 us; speedup vs baseline: 1.8813x; 1.8813x over previous
//
#include <hip/hip_runtime.h>
#include <stdint.h>

// Problem constants
// B=8, R=40, L=128, IN=256, WDIM=512, DREL=15, F=200 (pad 256), HID=300

#define LK(x) ((x) > 0.f ? (x) : 0.01f*(x))

typedef __attribute__((ext_vector_type(8))) short s16x8;
typedef __attribute__((ext_vector_type(4))) float f32x4;

__device__ __forceinline__ unsigned short f2bf(float f) {
  union { float f; unsigned int u; } v; v.f = f;
  unsigned int u = v.u;
  return (unsigned short)((u + 0x7FFFu + ((u >> 16) & 1u)) >> 16);
}

__device__ __forceinline__ void gload_lds16(const void* g, void* l) {
  __builtin_amdgcn_global_load_lds(
      (const __attribute__((address_space(1))) unsigned int*)g,
      (__attribute__((address_space(3))) unsigned int*)l, 16, 0, 0);
}

// ---------------- Kernel A: small preps --------------------------------
// roles: bid 0..7 h[b][300]; 8..15 trans[b][200]; 16..79 word_h->bf16;
//        80..143 arc_W slices ->bf16; 144 RW^T bf16 [256][72]
__global__ __launch_bounds__(256) void k_prep(
    const float* __restrict__ e1, const float* __restrict__ e2,
    const float* __restrict__ rel, const float* __restrict__ aW,
    const float* __restrict__ ffW, const float* __restrict__ ffb,
    const float* __restrict__ itW, const float* __restrict__ itb,
    const float* __restrict__ wh,
    unsigned short* __restrict__ whbf, unsigned short* __restrict__ aw1,
    unsigned short* __restrict__ aw2, unsigned short* __restrict__ rwt,
    float* __restrict__ hg, float* __restrict__ trans)
{
  int bid = blockIdx.x, t = threadIdx.x;
  if (bid < 16) {
    __shared__ float in_lds[1024];
    int b = bid & 7;
    for (int k = t; k < 1024; k += 256)
      in_lds[k] = (k < 512) ? e1[b*512 + k] : e2[b*512 + (k - 512)];
    __syncthreads();
    if (bid < 8) {
      for (int o = t; o < 300; o += 256) {
        const float4* wr = (const float4*)(ffW + (size_t)o*1024);
        float acc = ffb[o];
        for (int k = 0; k < 256; ++k) {
          float4 w = wr[k]; float4 v = *(const float4*)&in_lds[k*4];
          acc += w.x*v.x + w.y*v.y + w.z*v.z + w.w*v.w;
        }
        hg[b*300 + o] = LK(acc);
      }
    } else {
      for (int o = t; o < 200; o += 256) {
        const float4* wr = (const float4*)(itW + (size_t)o*1024);
        float acc = itb[o];
        for (int k = 0; k < 256; ++k) {
          float4 w = wr[k]; float4 v = *(const float4*)&in_lds[k*4];
          acc += w.x*v.x + w.y*v.y + w.z*v.z + w.w*v.w;
        }
        trans[b*200 + o] = LK(acc);
      }
    }
  } else if (bid < 80) {
    int id0 = (bid - 16)*256 + t;
    for (int v = id0; v < 131072; v += 64*256) {
      float4 x = ((const float4*)wh)[v];
      unsigned short* dst = whbf + (size_t)v*4;
      dst[0] = f2bf(x.x); dst[1] = f2bf(x.y); dst[2] = f2bf(x.z); dst[3] = f2bf(x.w);
    }
  } else if (bid < 144) {
    int id0 = (bid - 80)*256 + t;
    for (int e = id0; e < 131072; e += 64*256) {
      int o = e >> 9, k = e & 511;
      aw1[e] = f2bf(aW[(size_t)o*1039 + k]);
      aw2[e] = f2bf(aW[(size_t)o*1039 + 512 + k]);
    }
  } else {
    int o = t;  // 256 threads, one o each
    for (int r = 0; r < 40; ++r) {
      float s = 0.f;
      for (int d = 0; d < 15; ++d) s += rel[r*15 + d] * aW[(size_t)o*1039 + 1024 + d];
      rwt[o*72 + r] = f2bf(s);
    }
    for (int r = 40; r < 72; ++r) rwt[o*72 + r] = 0;
  }
}

// ---------------- Kernel B: P/Q GEMMs (MFMA) ---------------------------
// C[o][n=(b,j)] = sum_k aw[o][k]*wh[n][k]; one 16x16 tile per wave, K=512
__global__ __launch_bounds__(256) void k_pq(
    const unsigned short* __restrict__ whbf,
    const unsigned short* __restrict__ aw1,
    const unsigned short* __restrict__ aw2,
    float* __restrict__ Pg, float* __restrict__ Qg)
{
  int bid = blockIdx.x, t = threadIdx.x;
  int g = bid >> 8;
  int wv = t >> 6, l = t & 63, lm = l & 15, hi = l >> 4;
  int tile = (bid & 255)*4 + wv;
  int ot = tile & 15, nt = tile >> 4;
  const unsigned short* A = g ? aw2 : aw1;
  float* out = g ? Qg : Pg;
  int orow = ot*16 + lm, n = nt*16 + lm;
  f32x4 acc = {0.f, 0.f, 0.f, 0.f};
  const unsigned short* ap = A + (size_t)orow*512 + hi*8;
  const unsigned short* bp = whbf + (size_t)n*512 + hi*8;
#pragma unroll
  for (int kk = 0; kk < 16; ++kk) {
    s16x8 af = *(const s16x8*)(ap + kk*32);
    s16x8 bf = *(const s16x8*)(bp + kk*32);
    acc = __builtin_amdgcn_mfma_f32_16x16x32_bf16(af, bf, acc, 0, 0, 0);
  }
#pragma unroll
  for (int r = 0; r < 4; ++r)
    out[(size_t)n*256 + ot*16 + hi*4 + r] = acc[r];
}

// ---------------- Kernel C: filter factory via MFMA --------------------
// GEMM: filt[row=(f,d,tap)][b] = leaky( fw1[row][0:300] . h[b][0:300] + fb1[row] )
// Block = 64 contiguous rows (coalesced 76.8 KB), K padded 320, N padded 16.
// A,B staged bf16 in LDS with XOR swizzle (byte ^= (row&7)<<4).
// Trailing 64 blocks zero-fill filtg rows f in [200,256).
__global__ __launch_bounds__(256) void k_filt(
    const float* __restrict__ fw1, const float* __restrict__ fb1,
    const float* __restrict__ hg, unsigned short* __restrict__ filtg)
{
  int bid = blockIdx.x, t = threadIdx.x;
  if (bid >= 7200) {   // zero-fill f in [200,256) for one (b,dc) slice
    int bdc = bid - 7200;
    char* dst = (char*)(filtg + ((size_t)(bdc*256 + 200))*296);
    uint4 z = {0,0,0,0};
    for (int i = t; i < 2072; i += 256)       // 56 rows * 592 B = 33,152 B
      *(uint4*)(dst + (size_t)i*16) = z;
    return;
  }
  __shared__ __align__(16) unsigned short Abuf[64*320];  // 40,960 B
  __shared__ __align__(16) unsigned short Bbuf[16*320];  // 10,240 B
  int r0 = bid*64;
  // B tile [n(16)][k(320)] bf16, swizzled; n>=8 or k>=300 -> 0
  for (int idx = t; idx < 640; idx += 256) {
    int n = idx / 40, kc = idx - (idx/40)*40;
    unsigned w[4];
#pragma unroll
    for (int j = 0; j < 8; j += 2) {
      int k = kc*8 + j;
      float a = (n < 8 && k   < 300) ? hg[n*300 + k]     : 0.f;
      float b = (n < 8 && k+1 < 300) ? hg[n*300 + k + 1] : 0.f;
      w[j>>1] = (unsigned)f2bf(a) | ((unsigned)f2bf(b) << 16);
    }
    int byte = (n*640 + kc*16) ^ ((n & 7) << 4);
    *(uint4*)((char*)Bbuf + byte) = *(uint4*)w;
  }
  // A tile: 4800 float4 chunks, fully coalesced from flat fw1
  const float4* src = (const float4*)(fw1 + (size_t)r0*300);
  for (int i = 0; i < 19; ++i) {
    int c4 = t + i*256;
    if (c4 < 4800) {
      float4 v = src[c4];
      int row = c4 / 75, k = (c4 - row*75)*4;
      unsigned lo  = (unsigned)f2bf(v.x) | ((unsigned)f2bf(v.y) << 16);
      unsigned hi2 = (unsigned)f2bf(v.z) | ((unsigned)f2bf(v.w) << 16);
      int byte = (row*640 + k*2) ^ ((row & 7) << 4);
      *(unsigned long long*)((char*)Abuf + byte) =
          (unsigned long long)lo | ((unsigned long long)hi2 << 32);
    }
  }
  // zero pad k in [300,320)
  for (int idx = t; idx < 320; idx += 256) {
    int row = idx / 5, c = idx - (idx/5)*5;
    int byte = (row*640 + 600 + c*8) ^ ((row & 7) << 4);
    *(unsigned long long*)((char*)Abuf + byte) = 0ULL;
  }
  __syncthreads();
  int wv = t >> 6, l = t & 63, lm = l & 15, hi = l >> 4;
  int arow = wv*16 + lm;
  f32x4 acc = {0.f, 0.f, 0.f, 0.f};
#pragma unroll
  for (int ks = 0; ks < 10; ++ks) {
    int abyte = (arow*640 + ks*64 + hi*16) ^ ((arow & 7) << 4);
    int bbyte = (lm*640   + ks*64 + hi*16) ^ ((lm   & 7) << 4);
    s16x8 af = *(const s16x8*)((char*)Abuf + abyte);
    s16x8 bf = *(const s16x8*)((char*)Bbuf + bbyte);
    acc = __builtin_amdgcn_mfma_f32_16x16x32_bf16(af, bf, acc, 0, 0, 0);
  }
  if (lm < 8) {
    int b = lm;
#pragma unroll
    for (int r = 0; r < 4; ++r) {
      int wrow = r0 + wv*16 + hi*4 + r;
      int f = wrow / 2304;
      int rem = wrow - f*2304;
      int d = rem / 9, tap = rem - (rem/9)*9;
      float v = LK(acc[r] + fb1[wrow]);
      filtg[((size_t)((b*8 + (d >> 5))*256 + f))*296 + tap*32 + (d & 31)] = f2bf(v);
    }
  }
}

// ---------------- Kernel 2: arc -> mem_bank ----------------------------
// block=(b,i). S via MFMA E^T[128x64] @ RW[64x256]; epilogue adds
// marg*(P+Q)+bias, leaky, writes mem_bank[b][i][j][d=o] bf16.
__global__ __launch_bounds__(256) void k_arc(
    const float* __restrict__ energy,
    const unsigned short* __restrict__ rwt,
    const float* __restrict__ Pg, const float* __restrict__ Qg,
    const float* __restrict__ arcb,
    unsigned short* __restrict__ memb)
{
  __shared__ unsigned short Et[128*72];  // [j][r], r padded to 72, zeros >=40
  __shared__ float mpart[256];
  __shared__ float qlds[256];
  __shared__ float blds[256];
  int bid = blockIdx.x, t = threadIdx.x;
  int b = bid >> 7, i = bid & 127;
  int jj = t & 127, half = t >> 7;
  float macc = 0.f;
  for (int rr = 0; rr < 20; ++rr) {
    int r = half*20 + rr;
    float e = energy[(((size_t)b*40 + r)*128 + i)*128 + jj];
    e = fmaxf(e, 0.f);
    macc += e;
    Et[jj*72 + r] = f2bf(e);
  }
  mpart[t] = macc;
  if (t < 128) {
#pragma unroll
    for (int r = 40; r < 72; ++r) Et[t*72 + r] = 0;
  }
  qlds[t] = Qg[((size_t)(b*128 + i))*256 + t];
  blds[t] = arcb[t];
  __syncthreads();

  int wv = t >> 6, l = t & 63, lm = l & 15, hi = l >> 4;
  unsigned short* mout = memb + ((size_t)(b*128 + i))*128*256;
  for (int otl = 0; otl < 4; ++otl) {
    int oc = (wv*4 + otl)*16 + lm;
    const unsigned short* rp = rwt + oc*72 + hi*8;
    s16x8 bf0 = *(const s16x8*)rp;
    s16x8 bf1 = *(const s16x8*)(rp + 32);
    float q = qlds[oc], bias = blds[oc];
    for (int jt = 0; jt < 8; ++jt) {
      const unsigned short* ep = &Et[(jt*16 + lm)*72 + hi*8];
      s16x8 af0 = *(const s16x8*)ep;
      s16x8 af1 = *(const s16x8*)(ep + 32);
      f32x4 acc = {0.f,0.f,0.f,0.f};
      acc = __builtin_amdgcn_mfma_f32_16x16x32_bf16(af0, bf0, acc, 0, 0, 0);
      acc = __builtin_amdgcn_mfma_f32_16x16x32_bf16(af1, bf1, acc, 0, 0, 0);
#pragma unroll
      for (int r = 0; r < 4; ++r) {
        int j = jt*16 + hi*4 + r;
        float m = mpart[j] + mpart[128 + j];
        float p = Pg[((size_t)(b*128 + j))*256 + oc];
        float v = acc[r] + m*(p + q) + bias;
        v = LK(v);
        mout[(size_t)j*256 + oc] = f2bf(v);
      }
    }
  }
}

// ---------------- Kernel D: conv + fused leaky/maxpool -----------------
// block=(b, y, fc). C[x(128)][f(64)] via mfma 16x16x32, K=d chunks of 32,
// 9 taps accumulated. filt staged linearly (global layout pre-padded to
// match LDS); mem staged with pre-swizzled per-lane global source.
__global__ __launch_bounds__(256, 2) void k_conv(
    const unsigned short* __restrict__ filtg,
    const unsigned short* __restrict__ memb,
    float* __restrict__ part)
{
  __shared__ __align__(16) char smem[63232];
  char* lds_filt = smem;            // 64 f * 592 B = 37888
  char* lds_mem  = smem + 37888;    // 3 ky * 132 x * 64 B = 25344
  int bid = blockIdx.x, t = threadIdx.x;
  int y = bid % 126;
  int tmp = bid / 126;
  int fc = tmp & 3, b = tmp >> 2;
  int wv = t >> 6, l = t & 63, lm = l & 15, hi = l >> 4;
  int wx = wv & 1, wf = wv >> 1;

  f32x4 zero = {0.f,0.f,0.f,0.f};
  f32x4 acc[4][2];
#pragma unroll
  for (int xt = 0; xt < 4; ++xt) { acc[xt][0] = zero; acc[xt][1] = zero; }

  for (int dc = 0; dc < 8; ++dc) {
    const char* fs = (const char*)filtg + ((size_t)((b*8 + dc)*256 + fc*64))*592;
    for (int c = wv; c < 37; c += 4)
      gload_lds16(fs + ((size_t)c*64 + l)*16, lds_filt + c*1024);
    for (int c = wv; c < 25; c += 4) {
      int id = c*64 + l;
      if (id < 1584) {
        int ky = (id >= 1056) ? 2 : ((id >= 528) ? 1 : 0);
        int rem = id - ky*528;
        int x = rem >> 2, s = rem & 3;
        int cs = s ^ ((x >> 1) & 3);          // swizzled source chunk
        int xs = (x < 128) ? x : 127;          // clamp (discard columns)
        const char* ms = (const char*)memb +
            (((((size_t)(b*128 + y + ky))*128 + xs)*256) + dc*32 + cs*8)*2;
        gload_lds16(ms, lds_mem + c*1024);
      }
    }
    __syncthreads();
#pragma unroll
    for (int tap = 0; tap < 9; ++tap) {
      int ky = tap / 3, kx = tap - ky*3;
      s16x8 bfr[2];
#pragma unroll
      for (int ft = 0; ft < 2; ++ft)
        bfr[ft] = *(const s16x8*)(lds_filt + (wf*32 + ft*16 + lm)*592 + tap*64 + hi*16);
#pragma unroll
      for (int xt = 0; xt < 4; ++xt) {
        int x = wx*64 + xt*16 + lm + kx;
        int slot = hi ^ ((x >> 1) & 3);
        s16x8 af = *(const s16x8*)(lds_mem + ((ky*132 + x)*4 + slot)*16);
        acc[xt][0] = __builtin_amdgcn_mfma_f32_16x16x32_bf16(af, bfr[0], acc[xt][0], 0,0,0);
        acc[xt][1] = __builtin_amdgcn_mfma_f32_16x16x32_bf16(af, bfr[1], acc[xt][1], 0,0,0);
      }
    }
    __syncthreads();
  }

  // per-f max over this block's (x,y) footprint; leaky applied after max
  float pm0 = -3.4e38f, pm1 = -3.4e38f;
#pragma unroll
  for (int xt = 0; xt < 4; ++xt) {
    int xb = wx*64 + xt*16 + hi*4;
#pragma unroll
    for (int r = 0; r < 4; ++r) {
      if (xb + r < 126) {
        pm0 = fmaxf(pm0, acc[xt][0][r]);
        pm1 = fmaxf(pm1, acc[xt][1][r]);
      }
    }
  }
  pm0 = fmaxf(pm0, __shfl_xor(pm0, 16));
  pm0 = fmaxf(pm0, __shfl_xor(pm0, 32));
  pm1 = fmaxf(pm1, __shfl_xor(pm1, 16));
  pm1 = fmaxf(pm1, __shfl_xor(pm1, 32));
  float* red = (float*)smem;   // reuse LDS (after final barrier above)
  if (l < 16) {
    red[(wf*2 + wx)*32 + lm]      = pm0;
    red[(wf*2 + wx)*32 + 16 + lm] = pm1;
  }
  __syncthreads();
  if (t < 64) {
    int wfi = t >> 5, fi = t & 31;
    float v = fmaxf(red[(wfi*2 + 0)*32 + fi], red[(wfi*2 + 1)*32 + fi]);
    v = LK(v);
    part[((size_t)(b*126 + y))*256 + fc*64 + t] = v;
  }
}

// ---------------- Final: reduce over y, add transformed ----------------
__global__ __launch_bounds__(256) void k_final(
    const float* __restrict__ part, const float* __restrict__ trans,
    float* __restrict__ out)
{
  int b = blockIdx.x, t = threadIdx.x;
  if (t < 200) {
    float m = -3.4e38f;
    for (int yy = 0; yy < 126; ++yy)
      m = fmaxf(m, part[((size_t)(b*126 + yy))*256 + t]);
    out[b*200 + t] = trans[b*200 + t] + m;
  }
}

extern "C" void kernel_launch(void* const* d_in, const int* in_sizes, int n_in,
                              void* d_out, int out_size, void* d_ws, size_t ws_size,
                              hipStream_t stream)
{
  (void)in_sizes; (void)n_in; (void)out_size; (void)ws_size;
  const float* energy = (const float*)d_in[0];
  const float* word_h = (const float*)d_in[1];
  const float* e1     = (const float*)d_in[2];
  const float* e2     = (const float*)d_in[3];
  // d_in[4] sent_len unused
  const float* rel    = (const float*)d_in[5];
  const float* aW     = (const float*)d_in[6];
  const float* arcb   = (const float*)d_in[7];
  const float* ffW    = (const float*)d_in[8];
  const float* ffb    = (const float*)d_in[9];
  const float* fw1    = (const float*)d_in[10];
  const float* fb1    = (const float*)d_in[11];
  const float* itW    = (const float*)d_in[12];
  const float* itb    = (const float*)d_in[13];

  char* ws = (char*)d_ws;   // total required: 81,563,264 bytes
  unsigned short* whbf  = (unsigned short*)(ws + 0);         // 1,048,576
  unsigned short* aw1   = (unsigned short*)(ws + 1048576);   //   262,144
  unsigned short* aw2   = (unsigned short*)(ws + 1310720);   //   262,144
  unsigned short* rwt   = (unsigned short*)(ws + 1572864);   //    36,864
  float*          hg    = (float*)(ws + 1609728);            //     9,600
  float*          trans = (float*)(ws + 1619328);            //     6,400
  float*          Pg    = (float*)(ws + 1625728);            // 1,048,576
  float*          Qg    = (float*)(ws + 2674304);            // 1,048,576
  float*          part  = (float*)(ws + 3722880);            // 1,032,192
  unsigned short* filtg = (unsigned short*)(ws + 4755072);   // 9,699,328
  unsigned short* memb  = (unsigned short*)(ws + 14454400);  // 67,108,864

  k_prep <<<145, 256, 0, stream>>>(e1, e2, rel, aW, ffW, ffb, itW, itb, word_h,
                                   whbf, aw1, aw2, rwt, hg, trans);
  k_pq   <<<512, 256, 0, stream>>>(whbf, aw1, aw2, Pg, Qg);
  k_filt <<<7264, 256, 0, stream>>>(fw1, fb1, hg, filtg);
  k_arc  <<<1024, 256, 0, stream>>>(energy, rwt, Pg, Qg, arcb, memb);
  k_conv <<<4032, 256, 0, stream>>>(filtg, memb, part);
  k_final<<<8, 256, 0, stream>>>(part, trans, (float*)d_out);
}

// Round 3
// 433.219 us; speedup vs baseline: 2.1078x; 1.1204x over previous
//
#include <hip/hip_runtime.h>
#include <stdint.h>

// Problem constants
// B=8, R=40, L=128, IN=256, WDIM=512, DREL=15, F=200 (pad 256), HID=300

#define LK(x) ((x) > 0.f ? (x) : 0.01f*(x))

typedef __attribute__((ext_vector_type(8))) short s16x8;
typedef __attribute__((ext_vector_type(4))) float f32x4;

__device__ __forceinline__ unsigned short f2bf(float f) {
  union { float f; unsigned int u; } v; v.f = f;
  unsigned int u = v.u;
  return (unsigned short)((u + 0x7FFFu + ((u >> 16) & 1u)) >> 16);
}

__device__ __forceinline__ void gload_lds16(const void* g, void* l) {
  __builtin_amdgcn_global_load_lds(
      (const __attribute__((address_space(1))) unsigned int*)g,
      (__attribute__((address_space(3))) unsigned int*)l, 16, 0, 0);
}

// ---------------- Kernel A: small preps --------------------------------
// roles: bid 0..7 h[b][300]; 8..15 trans[b][200]; 16..79 word_h->bf16;
//        80..143 arc_W slices ->bf16; 144 RW^T bf16 [256][72]
__global__ __launch_bounds__(256) void k_prep(
    const float* __restrict__ e1, const float* __restrict__ e2,
    const float* __restrict__ rel, const float* __restrict__ aW,
    const float* __restrict__ ffW, const float* __restrict__ ffb,
    const float* __restrict__ itW, const float* __restrict__ itb,
    const float* __restrict__ wh,
    unsigned short* __restrict__ whbf, unsigned short* __restrict__ aw1,
    unsigned short* __restrict__ aw2, unsigned short* __restrict__ rwt,
    float* __restrict__ hg, float* __restrict__ trans)
{
  int bid = blockIdx.x, t = threadIdx.x;
  if (bid < 16) {
    __shared__ float in_lds[1024];
    int b = bid & 7;
    for (int k = t; k < 1024; k += 256)
      in_lds[k] = (k < 512) ? e1[b*512 + k] : e2[b*512 + (k - 512)];
    __syncthreads();
    if (bid < 8) {
      for (int o = t; o < 300; o += 256) {
        const float4* wr = (const float4*)(ffW + (size_t)o*1024);
        float acc = ffb[o];
        for (int k = 0; k < 256; ++k) {
          float4 w = wr[k]; float4 v = *(const float4*)&in_lds[k*4];
          acc += w.x*v.x + w.y*v.y + w.z*v.z + w.w*v.w;
        }
        hg[b*300 + o] = LK(acc);
      }
    } else {
      for (int o = t; o < 200; o += 256) {
        const float4* wr = (const float4*)(itW + (size_t)o*1024);
        float acc = itb[o];
        for (int k = 0; k < 256; ++k) {
          float4 w = wr[k]; float4 v = *(const float4*)&in_lds[k*4];
          acc += w.x*v.x + w.y*v.y + w.z*v.z + w.w*v.w;
        }
        trans[b*200 + o] = LK(acc);
      }
    }
  } else if (bid < 80) {
    int id0 = (bid - 16)*256 + t;
    for (int v = id0; v < 131072; v += 64*256) {
      float4 x = ((const float4*)wh)[v];
      unsigned short* dst = whbf + (size_t)v*4;
      dst[0] = f2bf(x.x); dst[1] = f2bf(x.y); dst[2] = f2bf(x.z); dst[3] = f2bf(x.w);
    }
  } else if (bid < 144) {
    int id0 = (bid - 80)*256 + t;
    for (int e = id0; e < 131072; e += 64*256) {
      int o = e >> 9, k = e & 511;
      aw1[e] = f2bf(aW[(size_t)o*1039 + k]);
      aw2[e] = f2bf(aW[(size_t)o*1039 + 512 + k]);
    }
  } else {
    int o = t;  // 256 threads, one o each
    for (int r = 0; r < 40; ++r) {
      float s = 0.f;
      for (int d = 0; d < 15; ++d) s += rel[r*15 + d] * aW[(size_t)o*1039 + 1024 + d];
      rwt[o*72 + r] = f2bf(s);
    }
    for (int r = 40; r < 72; ++r) rwt[o*72 + r] = 0;
  }
}

// ---------------- Kernel B: P/Q GEMMs (MFMA) ---------------------------
// C[o][n=(b,j)] = sum_k aw[o][k]*wh[n][k]; one 16x16 tile per wave, K=512
__global__ __launch_bounds__(256) void k_pq(
    const unsigned short* __restrict__ whbf,
    const unsigned short* __restrict__ aw1,
    const unsigned short* __restrict__ aw2,
    float* __restrict__ Pg, float* __restrict__ Qg)
{
  int bid = blockIdx.x, t = threadIdx.x;
  int g = bid >> 8;
  int wv = t >> 6, l = t & 63, lm = l & 15, hi = l >> 4;
  int tile = (bid & 255)*4 + wv;
  int ot = tile & 15, nt = tile >> 4;
  const unsigned short* A = g ? aw2 : aw1;
  float* out = g ? Qg : Pg;
  int orow = ot*16 + lm, n = nt*16 + lm;
  f32x4 acc = {0.f, 0.f, 0.f, 0.f};
  const unsigned short* ap = A + (size_t)orow*512 + hi*8;
  const unsigned short* bp = whbf + (size_t)n*512 + hi*8;
#pragma unroll
  for (int kk = 0; kk < 16; ++kk) {
    s16x8 af = *(const s16x8*)(ap + kk*32);
    s16x8 bf = *(const s16x8*)(bp + kk*32);
    acc = __builtin_amdgcn_mfma_f32_16x16x32_bf16(af, bf, acc, 0, 0, 0);
  }
#pragma unroll
  for (int r = 0; r < 4; ++r)
    out[(size_t)n*256 + ot*16 + hi*4 + r] = acc[r];
}

// ---------------- Kernel C: filter factory via MFMA --------------------
// GEMM: filt[row=(f,d,tap)][b] = leaky( fw1[row][0:300] . h[b][0:300] + fb1[row] )
// Block = 64 contiguous rows (coalesced 76.8 KB), K padded 320, N padded 16.
// A,B staged bf16 in LDS with XOR swizzle (byte ^= (row&7)<<4).
// Trailing 64 blocks zero-fill filtg rows f in [200,256).
__global__ __launch_bounds__(256) void k_filt(
    const float* __restrict__ fw1, const float* __restrict__ fb1,
    const float* __restrict__ hg, unsigned short* __restrict__ filtg)
{
  int bid = blockIdx.x, t = threadIdx.x;
  if (bid >= 7200) {   // zero-fill f in [200,256) for one (b,dc) slice
    int bdc = bid - 7200;
    char* dst = (char*)(filtg + ((size_t)(bdc*256 + 200))*296);
    uint4 z = {0,0,0,0};
    for (int i = t; i < 2072; i += 256)       // 56 rows * 592 B = 33,152 B
      *(uint4*)(dst + (size_t)i*16) = z;
    return;
  }
  __shared__ __align__(16) unsigned short Abuf[64*320];  // 40,960 B
  __shared__ __align__(16) unsigned short Bbuf[16*320];  // 10,240 B
  int r0 = bid*64;
  // B tile [n(16)][k(320)] bf16, swizzled; n>=8 or k>=300 -> 0
  for (int idx = t; idx < 640; idx += 256) {
    int n = idx / 40, kc = idx - (idx/40)*40;
    unsigned w[4];
#pragma unroll
    for (int j = 0; j < 8; j += 2) {
      int k = kc*8 + j;
      float a = (n < 8 && k   < 300) ? hg[n*300 + k]     : 0.f;
      float b = (n < 8 && k+1 < 300) ? hg[n*300 + k + 1] : 0.f;
      w[j>>1] = (unsigned)f2bf(a) | ((unsigned)f2bf(b) << 16);
    }
    int byte = (n*640 + kc*16) ^ ((n & 7) << 4);
    *(uint4*)((char*)Bbuf + byte) = *(uint4*)w;
  }
  // A tile: 4800 float4 chunks, fully coalesced from flat fw1
  const float4* src = (const float4*)(fw1 + (size_t)r0*300);
  for (int i = 0; i < 19; ++i) {
    int c4 = t + i*256;
    if (c4 < 4800) {
      float4 v = src[c4];
      int row = c4 / 75, k = (c4 - row*75)*4;
      unsigned lo  = (unsigned)f2bf(v.x) | ((unsigned)f2bf(v.y) << 16);
      unsigned hi2 = (unsigned)f2bf(v.z) | ((unsigned)f2bf(v.w) << 16);
      int byte = (row*640 + k*2) ^ ((row & 7) << 4);
      *(unsigned long long*)((char*)Abuf + byte) =
          (unsigned long long)lo | ((unsigned long long)hi2 << 32);
    }
  }
  // zero pad k in [300,320)
  for (int idx = t; idx < 320; idx += 256) {
    int row = idx / 5, c = idx - (idx/5)*5;
    int byte = (row*640 + 600 + c*8) ^ ((row & 7) << 4);
    *(unsigned long long*)((char*)Abuf + byte) = 0ULL;
  }
  __syncthreads();
  int wv = t >> 6, l = t & 63, lm = l & 15, hi = l >> 4;
  int arow = wv*16 + lm;
  f32x4 acc = {0.f, 0.f, 0.f, 0.f};
#pragma unroll
  for (int ks = 0; ks < 10; ++ks) {
    int abyte = (arow*640 + ks*64 + hi*16) ^ ((arow & 7) << 4);
    int bbyte = (lm*640   + ks*64 + hi*16) ^ ((lm   & 7) << 4);
    s16x8 af = *(const s16x8*)((char*)Abuf + abyte);
    s16x8 bf = *(const s16x8*)((char*)Bbuf + bbyte);
    acc = __builtin_amdgcn_mfma_f32_16x16x32_bf16(af, bf, acc, 0, 0, 0);
  }
  if (lm < 8) {
    int b = lm;
#pragma unroll
    for (int r = 0; r < 4; ++r) {
      int wrow = r0 + wv*16 + hi*4 + r;
      int f = wrow / 2304;
      int rem = wrow - f*2304;
      int d = rem / 9, tap = rem - (rem/9)*9;
      float v = LK(acc[r] + fb1[wrow]);
      filtg[((size_t)((b*8 + (d >> 5))*256 + f))*296 + tap*32 + (d & 31)] = f2bf(v);
    }
  }
}

// ---------------- Kernel 2: arc -> mem_bank ----------------------------
// block=(b,i). S via MFMA E^T[128x64] @ RW[64x256]; epilogue adds
// marg*(P+Q)+bias, leaky, writes mem_bank[b][i][j][d=o] bf16.
__global__ __launch_bounds__(256) void k_arc(
    const float* __restrict__ energy,
    const unsigned short* __restrict__ rwt,
    const float* __restrict__ Pg, const float* __restrict__ Qg,
    const float* __restrict__ arcb,
    unsigned short* __restrict__ memb)
{
  __shared__ unsigned short Et[128*72];  // [j][r], r padded to 72, zeros >=40
  __shared__ float mpart[256];
  __shared__ float qlds[256];
  __shared__ float blds[256];
  int bid = blockIdx.x, t = threadIdx.x;
  int b = bid >> 7, i = bid & 127;
  int jj = t & 127, half = t >> 7;
  float macc = 0.f;
  for (int rr = 0; rr < 20; ++rr) {
    int r = half*20 + rr;
    float e = energy[(((size_t)b*40 + r)*128 + i)*128 + jj];
    e = fmaxf(e, 0.f);
    macc += e;
    Et[jj*72 + r] = f2bf(e);
  }
  mpart[t] = macc;
  if (t < 128) {
#pragma unroll
    for (int r = 40; r < 72; ++r) Et[t*72 + r] = 0;
  }
  qlds[t] = Qg[((size_t)(b*128 + i))*256 + t];
  blds[t] = arcb[t];
  __syncthreads();

  int wv = t >> 6, l = t & 63, lm = l & 15, hi = l >> 4;
  unsigned short* mout = memb + ((size_t)(b*128 + i))*128*256;
  for (int otl = 0; otl < 4; ++otl) {
    int oc = (wv*4 + otl)*16 + lm;
    const unsigned short* rp = rwt + oc*72 + hi*8;
    s16x8 bf0 = *(const s16x8*)rp;
    s16x8 bf1 = *(const s16x8*)(rp + 32);
    float q = qlds[oc], bias = blds[oc];
    for (int jt = 0; jt < 8; ++jt) {
      const unsigned short* ep = &Et[(jt*16 + lm)*72 + hi*8];
      s16x8 af0 = *(const s16x8*)ep;
      s16x8 af1 = *(const s16x8*)(ep + 32);
      f32x4 acc = {0.f,0.f,0.f,0.f};
      acc = __builtin_amdgcn_mfma_f32_16x16x32_bf16(af0, bf0, acc, 0, 0, 0);
      acc = __builtin_amdgcn_mfma_f32_16x16x32_bf16(af1, bf1, acc, 0, 0, 0);
#pragma unroll
      for (int r = 0; r < 4; ++r) {
        int j = jt*16 + hi*4 + r;
        float m = mpart[j] + mpart[128 + j];
        float p = Pg[((size_t)(b*128 + j))*256 + oc];
        float v = acc[r] + m*(p + q) + bias;
        v = LK(v);
        mout[(size_t)j*256 + oc] = f2bf(v);
      }
    }
  }
}

// ---------------- Kernel D: conv + fused leaky/maxpool -----------------
// block=(b, y-pair, fc). YB=2 output rows per block: C[yb][x(128)][f(64)]
// via mfma 16x16x32, K=d chunks of 32, 9 taps accumulated; 144 MFMA per
// barrier pair. 4 mem rows staged (pre-swizzled per-lane global source),
// filt staged linearly. Chunked XCD swizzle pins each b to one XCD's L2.
__global__ __launch_bounds__(256, 2) void k_conv(
    const unsigned short* __restrict__ filtg,
    const unsigned short* __restrict__ memb,
    float* __restrict__ part)
{
  __shared__ __align__(16) char smem[71680];
  char* lds_filt = smem;            // 64 f * 592 B = 37888
  char* lds_mem  = smem + 37888;    // 4 ky * 132 x * 64 B = 33792
  int t = threadIdx.x;
  // bijective chunked XCD swizzle: 2016 blocks, 252 per XCD
  int bid = (blockIdx.x & 7)*252 + (blockIdx.x >> 3);
  int yp = bid % 63;
  int tmp = bid / 63;
  int fc = tmp & 3, b = tmp >> 2;
  int y0 = yp*2;
  int wv = t >> 6, l = t & 63, lm = l & 15, hi = l >> 4;
  int wx = wv & 1, wf = wv >> 1;

  f32x4 zero = {0.f,0.f,0.f,0.f};
  f32x4 acc[2][4][2];
#pragma unroll
  for (int yb = 0; yb < 2; ++yb)
#pragma unroll
    for (int xt = 0; xt < 4; ++xt) { acc[yb][xt][0] = zero; acc[yb][xt][1] = zero; }

  for (int dc = 0; dc < 8; ++dc) {
    const char* fs = (const char*)filtg + ((size_t)((b*8 + dc)*256 + fc*64))*592;
    for (int c = wv; c < 37; c += 4)
      gload_lds16(fs + ((size_t)c*64 + l)*16, lds_filt + c*1024);
    for (int c = wv; c < 33; c += 4) {
      int id = c*64 + l;                      // 0..2111 = 4 rows * 528
      int ky = id / 528;
      int rem = id - ky*528;
      int x = rem >> 2, s = rem & 3;
      int cs = s ^ ((x >> 1) & 3);            // swizzled source chunk
      int xs = (x < 128) ? x : 127;           // clamp (discard columns)
      const char* ms = (const char*)memb +
          (((((size_t)(b*128 + y0 + ky))*128 + xs)*256) + dc*32 + cs*8)*2;
      gload_lds16(ms, lds_mem + c*1024);
    }
    __syncthreads();
#pragma unroll
    for (int tap = 0; tap < 9; ++tap) {
      int ky = tap / 3, kx = tap - ky*3;
      s16x8 bfr[2];
#pragma unroll
      for (int ft = 0; ft < 2; ++ft)
        bfr[ft] = *(const s16x8*)(lds_filt + (wf*32 + ft*16 + lm)*592 + tap*64 + hi*16);
#pragma unroll
      for (int yb = 0; yb < 2; ++yb) {
#pragma unroll
        for (int xt = 0; xt < 4; ++xt) {
          int x = wx*64 + xt*16 + lm + kx;
          int slot = hi ^ ((x >> 1) & 3);
          s16x8 af = *(const s16x8*)(lds_mem + (((yb + ky)*132 + x)*4 + slot)*16);
          acc[yb][xt][0] = __builtin_amdgcn_mfma_f32_16x16x32_bf16(af, bfr[0], acc[yb][xt][0], 0,0,0);
          acc[yb][xt][1] = __builtin_amdgcn_mfma_f32_16x16x32_bf16(af, bfr[1], acc[yb][xt][1], 0,0,0);
        }
      }
    }
    __syncthreads();
  }

  // per-f max over this block's (x) footprint per yb; leaky applied after max
  float pm[2][2];
  pm[0][0] = pm[0][1] = pm[1][0] = pm[1][1] = -3.4e38f;
#pragma unroll
  for (int yb = 0; yb < 2; ++yb)
#pragma unroll
    for (int xt = 0; xt < 4; ++xt) {
      int xb = wx*64 + xt*16 + hi*4;
#pragma unroll
      for (int r = 0; r < 4; ++r) {
        if (xb + r < 126) {
          pm[yb][0] = fmaxf(pm[yb][0], acc[yb][xt][0][r]);
          pm[yb][1] = fmaxf(pm[yb][1], acc[yb][xt][1][r]);
        }
      }
    }
#pragma unroll
  for (int yb = 0; yb < 2; ++yb)
#pragma unroll
    for (int ft = 0; ft < 2; ++ft) {
      pm[yb][ft] = fmaxf(pm[yb][ft], __shfl_xor(pm[yb][ft], 16));
      pm[yb][ft] = fmaxf(pm[yb][ft], __shfl_xor(pm[yb][ft], 32));
    }
  float* red = (float*)smem;   // reuse LDS (after final barrier above)
  if (l < 16) {
#pragma unroll
    for (int yb = 0; yb < 2; ++yb)
#pragma unroll
      for (int ft = 0; ft < 2; ++ft)
        red[(yb*4 + wf*2 + wx)*32 + ft*16 + lm] = pm[yb][ft];
  }
  __syncthreads();
  if (t < 128) {
    int yb = t >> 6, tt = t & 63;
    int wfi = tt >> 5, fi = tt & 31;
    float v = fmaxf(red[(yb*4 + wfi*2 + 0)*32 + fi], red[(yb*4 + wfi*2 + 1)*32 + fi]);
    v = LK(v);
    part[((size_t)(b*126 + y0 + yb))*256 + fc*64 + tt] = v;
  }
}

// ---------------- Final: reduce over y, add transformed ----------------
__global__ __launch_bounds__(256) void k_final(
    const float* __restrict__ part, const float* __restrict__ trans,
    float* __restrict__ out)
{
  int b = blockIdx.x, t = threadIdx.x;
  if (t < 200) {
    float m = -3.4e38f;
    for (int yy = 0; yy < 126; ++yy)
      m = fmaxf(m, part[((size_t)(b*126 + yy))*256 + t]);
    out[b*200 + t] = trans[b*200 + t] + m;
  }
}

extern "C" void kernel_launch(void* const* d_in, const int* in_sizes, int n_in,
                              void* d_out, int out_size, void* d_ws, size_t ws_size,
                              hipStream_t stream)
{
  (void)in_sizes; (void)n_in; (void)out_size; (void)ws_size;
  const float* energy = (const float*)d_in[0];
  const float* word_h = (const float*)d_in[1];
  const float* e1     = (const float*)d_in[2];
  const float* e2     = (const float*)d_in[3];
  // d_in[4] sent_len unused
  const float* rel    = (const float*)d_in[5];
  const float* aW     = (const float*)d_in[6];
  const float* arcb   = (const float*)d_in[7];
  const float* ffW    = (const float*)d_in[8];
  const float* ffb    = (const float*)d_in[9];
  const float* fw1    = (const float*)d_in[10];
  const float* fb1    = (const float*)d_in[11];
  const float* itW    = (const float*)d_in[12];
  const float* itb    = (const float*)d_in[13];

  char* ws = (char*)d_ws;   // total required: 81,563,264 bytes
  unsigned short* whbf  = (unsigned short*)(ws + 0);         // 1,048,576
  unsigned short* aw1   = (unsigned short*)(ws + 1048576);   //   262,144
  unsigned short* aw2   = (unsigned short*)(ws + 1310720);   //   262,144
  unsigned short* rwt   = (unsigned short*)(ws + 1572864);   //    36,864
  float*          hg    = (float*)(ws + 1609728);            //     9,600
  float*          trans = (float*)(ws + 1619328);            //     6,400
  float*          Pg    = (float*)(ws + 1625728);            // 1,048,576
  float*          Qg    = (float*)(ws + 2674304);            // 1,048,576
  float*          part  = (float*)(ws + 3722880);            // 1,032,192
  unsigned short* filtg = (unsigned short*)(ws + 4755072);   // 9,699,328
  unsigned short* memb  = (unsigned short*)(ws + 14454400);  // 67,108,864

  k_prep <<<145, 256, 0, stream>>>(e1, e2, rel, aW, ffW, ffb, itW, itb, word_h,
                                   whbf, aw1, aw2, rwt, hg, trans);
  k_pq   <<<512, 256, 0, stream>>>(whbf, aw1, aw2, Pg, Qg);
  k_filt <<<7264, 256, 0, stream>>>(fw1, fb1, hg, filtg);
  k_arc  <<<1024, 256, 0, stream>>>(energy, rwt, Pg, Qg, arcb, memb);
  k_conv <<<2016, 256, 0, stream>>>(filtg, memb, part);
  k_final<<<8, 256, 0, stream>>>(part, trans, (float*)d_out);
}